// Round 6
// baseline (630.748 us; speedup 1.0000x reference)
//
#include <hip/hip_runtime.h>
#include <hip/hip_bf16.h>
#include <stdint.h>

// Problem: T=128, B=32, D=1024, H=1024 LSTM unroll, fp32 in/out.
#define T_STEPS 128
#define BATCH   32
#define DIM     1024
#define HID     1024
#define NGATE   4096            // 4*H
#define MROWS   4096            // T*B
#define NWGR    64              // persistent recurrence workgroups (16 units each)

typedef unsigned int u32;
typedef __attribute__((ext_vector_type(8)))  __bf16 bf16x8;
typedef __attribute__((ext_vector_type(4)))  float  f32x4;
typedef __attribute__((ext_vector_type(16))) float  f32x16;
typedef __attribute__((ext_vector_type(4)))  u32    u32x4;

__device__ __forceinline__ unsigned short f2bf(float f) {
    u32 x = __float_as_uint(f);
    return (unsigned short)((x + 0x7fffu + ((x >> 16) & 1u)) >> 16);  // RNE
}
__device__ __forceinline__ float sigf(float x) {
    return 1.0f / (1.0f + __expf(-x));
}
__device__ __forceinline__ float tanh_fast(float x) {
    float ax = fabsf(x);
    float e  = __expf(-2.0f * ax);           // in (0,1], no overflow
    float t  = (1.0f - e) / (1.0f + e);
    return copysignf(t, x);
}
__device__ __forceinline__ u32 umax2(u32 a, u32 b) { return a > b ? a : b; }

// DEVICE-scope (agent) store: sc1 only. Bypasses L1 + per-XCD L2, served by
// the memory-side Infinity Cache. hb is ONLY touched through sc1 ops during
// lstm_rec -> no line of it ever lives in any L2 -> no fences needed.
__device__ __forceinline__ void store_u32_coh(u32* p, u32 v) {
    asm volatile("global_store_dword %0, %1, off sc1" :: "v"(p), "v"(v) : "memory");
}

// ---------------- prep kernels ----------------

__global__ void cast_f32_bf16(const float* __restrict__ in,
                              unsigned short* __restrict__ out, int n) {
    int idx = (blockIdx.x * blockDim.x + threadIdx.x) * 4;
    if (idx + 3 < n) {
        float4 v = *(const float4*)(in + idx);
        ushort4 o;
        o.x = f2bf(v.x); o.y = f2bf(v.y); o.z = f2bf(v.z); o.w = f2bf(v.w);
        *(ushort4*)(out + idx) = o;
    }
}

// sentinel fill: 0xFFFFFFFF = packed (NaN|NaN) bf16 pair; h is always finite
// and in (-1,1), so a real packed h can never equal the sentinel.
__global__ void fill_sentinel(u32* __restrict__ p, int n) {
    int i = (blockIdx.x * blockDim.x + threadIdx.x) * 4;
    if (i + 3 < n) {
        u32x4 v = {0xFFFFFFFFu, 0xFFFFFFFFu, 0xFFFFFFFFu, 0xFFFFFFFFu};
        *(u32x4*)(p + i) = v;
    }
}

// in: R x C fp32 (row-major) -> out: C x R bf16 (row-major transpose)
__global__ void transpose_cast(const float* __restrict__ in,
                               unsigned short* __restrict__ out, int R, int C) {
    __shared__ float tile[32][33];
    int c0 = blockIdx.x * 32, r0 = blockIdx.y * 32;
    int tx = threadIdx.x, ty = threadIdx.y;     // 32 x 8
#pragma unroll
    for (int i = 0; i < 4; ++i)
        tile[ty + i * 8][tx] = in[(size_t)(r0 + ty + i * 8) * C + c0 + tx];
    __syncthreads();
#pragma unroll
    for (int i = 0; i < 4; ++i)
        out[(size_t)(c0 + ty + i * 8) * R + r0 + tx] = f2bf(tile[tx][ty + i * 8]);
}

// ---------------- phase 1: Gp = perm(x @ Wx + b)  (bf16 MFMA, fp32 out) ----------------
// A: MROWS x DIM bf16 (x), BT: NGATE x DIM bf16 (WxT).
// Output in GATE-MINOR panels for the 64-WG recurrence:
//   orig col co = g*1024 + hu  ->  panel wg = hu>>4 (16 units), local unit u = hu&15,
//   panel col cp = u*4 + g  (so 4 gates of a unit are CONTIGUOUS -> f32x4 epilogue)
//   Gp[((size_t)wg*MROWS + row)*64 + cp]
__global__ __launch_bounds__(256) void gemm_xw(
    const unsigned short* __restrict__ A,
    const unsigned short* __restrict__ BT,
    const float* __restrict__ bias,
    float* __restrict__ Gp) {
    __shared__ unsigned short As[128 * 32];
    __shared__ unsigned short Bs[128 * 32];
    int tid  = threadIdx.x;
    int wave = tid >> 6, lane = tid & 63;
    int q = lane >> 4, c = lane & 15;
    int wm = wave >> 1, wn = wave & 1;
    int tm = blockIdx.y * 128, tn = blockIdx.x * 128;

    f32x4 acc[4][4] = {};

    const int srow0 = tid >> 2;           // 0..63
    const int srow1 = 64 + (tid >> 2);    // 64..127
    const int scol  = (tid & 3) * 8;      // bf16 elems

    u32x4 ra0, ra1, rb0, rb1;
    ra0 = *(const u32x4*)(A  + (size_t)(tm + srow0) * DIM + scol);
    ra1 = *(const u32x4*)(A  + (size_t)(tm + srow1) * DIM + scol);
    rb0 = *(const u32x4*)(BT + (size_t)(tn + srow0) * DIM + scol);
    rb1 = *(const u32x4*)(BT + (size_t)(tn + srow1) * DIM + scol);

    for (int kk = 0; kk < 32; ++kk) {
        __syncthreads();
        *(u32x4*)(As + srow0 * 32 + scol) = ra0;
        *(u32x4*)(As + srow1 * 32 + scol) = ra1;
        *(u32x4*)(Bs + srow0 * 32 + scol) = rb0;
        *(u32x4*)(Bs + srow1 * 32 + scol) = rb1;
        __syncthreads();
        if (kk < 31) {
            int ko = (kk + 1) * 32 + scol;
            ra0 = *(const u32x4*)(A  + (size_t)(tm + srow0) * DIM + ko);
            ra1 = *(const u32x4*)(A  + (size_t)(tm + srow1) * DIM + ko);
            rb0 = *(const u32x4*)(BT + (size_t)(tn + srow0) * DIM + ko);
            rb1 = *(const u32x4*)(BT + (size_t)(tn + srow1) * DIM + ko);
        }
        bf16x8 af[4], bfv[4];
#pragma unroll
        for (int i = 0; i < 4; ++i) {
            af[i]  = *(const bf16x8*)(As + (wm * 64 + i * 16 + c) * 32 + q * 8);
            bfv[i] = *(const bf16x8*)(Bs + (wn * 64 + i * 16 + c) * 32 + q * 8);
        }
#pragma unroll
        for (int i = 0; i < 4; ++i)
#pragma unroll
            for (int j = 0; j < 4; ++j)
                acc[i][j] = __builtin_amdgcn_mfma_f32_16x16x32_bf16(
                    af[i], bfv[j], acc[i][j], 0, 0, 0);
    }
    // epilogue: C/D layout col = lane&15, row = quad*4 + reg; gate-minor store
#pragma unroll
    for (int j = 0; j < 4; ++j) {
        int co = tn + wn * 64 + j * 16 + c;
        float bj = bias[co];
        int g = co >> 10, hu = co & 1023;
        int wgr = hu >> 4, u = hu & 15;
        int cp = u * 4 + g;
#pragma unroll
        for (int i = 0; i < 4; ++i) {
            int row0 = tm + wm * 64 + i * 16 + q * 4;
#pragma unroll
            for (int r = 0; r < 4; ++r)
                Gp[((size_t)wgr * MROWS + row0 + r) * 64 + cp] = acc[i][j][r] + bj;
        }
    }
}

// ---------------- phase 2: persistent recurrence, batch-split pipeline ----------------
// 64 WGs x 512 threads (8 waves). WG wg owns 16 hidden units.
//
// R6 STRUCTURE: the recurrence is ELEMENTWISE IN BATCH -> batches 0-15 (half 0)
// and 16-31 (half 1) are two independent 16-batch LSTMs. Run them as two
// alternating phases per step: while half X's freshly-stored h propagates
// through the IC (t_vis ~2500-3000cy, the serial cost R0-R5 could not remove),
// the WG computes half 1-X's entire phase. Published h gets a full phase
// (~1700cy) of aging before anyone polls it -> poll ~= plain IC load.
//
// Per phase: poll 4KB/wave -> stage Hs rows X*16.. (rows = GLOBAL batch; halves
// occupy disjoint rows, no double-buffer) -> barA -> MFMA all 32 rows (other
// half's rows are stale -> those output rows DISCARDED; no cross-row
// contamination in MFMA) -> dump SlT only valid regs (rg = 2X..2X+1, static
// via unrolled X) -> barB -> epilogue by waves wv>>2 == X (wave-uniform).
// Race audit: barB(X) separates MFMA(X) Hs reads from the next phase's stage
// writes; barA separates stage from MFMA reads; SlT reuse separated by barA
// of the next phase (each thread's epilogue reads precede its next barA).
//
// DEFERRED-ISSUE HOOK (fixes R4/R5's exposed waits): the epilogue publishes h
// ONLY (IC ack ~free in the next poll's drain = pacing). The out-store (HBM
// ack ~900cy) and the Gp prefetch issue at the NEXT phase's post-poll point,
// so they age a full phase before any later vmcnt(0) can see them.
__global__ __launch_bounds__(512, 1) void lstm_rec(
    const unsigned short* __restrict__ WhT,   // NGATE x DIM bf16
    const float* __restrict__ Gp,             // gate-minor panels, 64 x 4096 x 64 fp32
    unsigned short* hb,                       // (T+1) x BATCH x HID bf16 (slot 0 unused)
    float* __restrict__ out) {                // T x BATCH x HID fp32
    __shared__ unsigned short Hs[32][1024];   // 64 KB, row = GLOBAL batch, XOR-swizzled
    __shared__ float SlT[8][16][64];          // 32 KB, [ks][local b][panel col]
    const int wg = blockIdx.x, tid = threadIdx.x;
    const int wv = tid >> 6, lane = tid & 63;
    const int ln = lane & 31, lh = lane >> 5;
    const int myhalf = wv >> 2;               // == batch>>4 for this thread

    // ---- stage B-fragments (Wh) into registers, once ----
    // B-frag (32x32x16): col = lane&31 = u8*4+g (gate-minor), k = wv*128 + kk*16 + lh*8 + j
    bf16x8 br0[8], br1[8];
    {
        const int u8 = ln >> 2, g = ln & 3;
        const unsigned short* w0 =
            WhT + (size_t)(g * HID + wg * 16 + 0 * 8 + u8) * DIM + wv * 128 + lh * 8;
        const unsigned short* w1 =
            WhT + (size_t)(g * HID + wg * 16 + 1 * 8 + u8) * DIM + wv * 128 + lh * 8;
#pragma unroll
        for (int kk = 0; kk < 8; ++kk) {
            br0[kk] = *(const bf16x8*)(w0 + kk * 16);
            br1[kk] = *(const bf16x8*)(w1 + kk * 16);
        }
    }

    // epilogue mapping: thread = (batch, u); ONE output per thread
    const int batch = tid >> 4, uu = tid & 15;   // batch GLOBAL 0..31
    float cs = 0.f;
    float hvp = 0.f;                          // pending out value (deferred store)
    // G prefetch for t=0 (gate-minor: f32x4 = 4 gates of unit uu)
    f32x4 ga = *(const f32x4*)(Gp + ((size_t)wg * MROWS + batch) * 64 + uu * 4);

    char* hs_base = (char*)&Hs[0][0];
    const int rxor = (ln & 15) << 4;          // read-side swizzle constant

    for (int t = 0; t < T_STEPS; ++t) {
#pragma unroll
        for (int X = 0; X < 2; ++X) {
            f32x16 acc0 = {}, acc1 = {};
            if (t > 0) {
                // ---- coalesced, sentinel-validated half-h load (wave-local retry) ----
                // slot t layout: batch*2048 + unit*2 bytes. Half X = bytes
                // [X*32K, X*32K+32K); wave wv owns 4KB = batches X*16+wv*2..+2.
                const char* p0 = (const char*)hb + ((size_t)t << 16) + (X << 15)
                               + (wv << 12) + (size_t)lane * 16;
                u32x4 h[4];
                for (;;) {
                    asm volatile(
                        "global_load_dwordx4 %0, %4, off sc1\n\t"
                        "global_load_dwordx4 %1, %4, off offset:1024 sc1\n\t"
                        "global_load_dwordx4 %2, %4, off offset:2048 sc1\n\t"
                        "global_load_dwordx4 %3, %4, off offset:3072 sc1\n\t"
                        "s_waitcnt vmcnt(0)"
                        : "=&v"(h[0]), "=&v"(h[1]), "=&v"(h[2]), "=&v"(h[3])
                        : "v"(p0)
                        : "memory");
                    u32 m = 0;
#pragma unroll
                    for (int i = 0; i < 4; ++i) {
                        u32 a = umax2(umax2(h[i][0], h[i][1]),
                                      umax2(h[i][2], h[i][3]));
                        m = umax2(m, a);
                    }
                    if (!__any((int)(m == 0xFFFFFFFFu))) break;
                }

                // ---- deferred-issue hook: previous phase's epilogue waves issue
                // their out-store + Gp prefetch NOW (post-poll -> a full phase of
                // aging before the next vmcnt(0) they meet). Wave-uniform branch.
                if (myhalf != X) {
                    const int to = X ? t : (t - 1);          // out row of pending hv
                    out[((size_t)to * BATCH + batch) * HID + wg * 16 + uu] = hvp;
                    const int tg = X ? ((t + 1 < T_STEPS) ? t + 1 : T_STEPS - 1) : t;
                    ga = *(const f32x4*)(Gp + ((size_t)wg * MROWS
                            + (size_t)tg * 32 + batch) * 64 + uu * 4);
                }

                // ---- stage into swizzled Hs rows X*16 + wv*2 + (j>>1) ----
#pragma unroll
                for (int j = 0; j < 4; ++j) {
                    int row  = X * 16 + (wv << 1) + (j >> 1);
                    int colb = ((j & 1) << 10) + lane * 16;
                    int off  = (row << 11) + (colb ^ ((row & 15) << 4));
                    *(u32x4*)(hs_base + off) = h[j];
                }
                asm volatile("s_waitcnt lgkmcnt(0)" ::: "memory");
                __builtin_amdgcn_s_barrier();            // barrier A: Hs half ready

                // ---- K-eighth: 8 A-reads, 16 MFMAs (each read feeds BOTH tiles) ----
                // A-frag rows = global batch 0..31; other half's rows stale -> discarded.
                const char* hrow = hs_base + (ln << 11);
#pragma unroll
                for (int kk = 0; kk < 8; ++kk) {
                    int cb = ((wv << 8) + (kk << 5) + (lh << 4)) ^ rxor;
                    bf16x8 a = *(const bf16x8*)(hrow + cb);
                    acc0 = __builtin_amdgcn_mfma_f32_32x32x16_bf16(a, br0[kk], acc0, 0, 0, 0);
                    acc1 = __builtin_amdgcn_mfma_f32_32x32x16_bf16(a, br1[kk], acc1, 0, 0, 0);
                }

                // ---- dump valid partials: rows b = rr + 8*rg + 4*lh in half X
                // <=> rg in {2X, 2X+1}; local bl = rr + 8*rg2 + 4*lh. Static idx.
#pragma unroll
                for (int rg2 = 0; rg2 < 2; ++rg2)
#pragma unroll
                    for (int rr = 0; rr < 4; ++rr) {
                        const int bl = rr + 8 * rg2 + 4 * lh;
                        SlT[wv][bl][ln]      = acc0[(2 * X + rg2) * 4 + rr];
                        SlT[wv][bl][32 + ln] = acc1[(2 * X + rg2) * 4 + rr];
                    }
                asm volatile("s_waitcnt lgkmcnt(0)" ::: "memory");
                __builtin_amdgcn_s_barrier();            // barrier B: SlT ready
            } else if (X == 1) {
                // t==0 hook slot (no poll at t==0): half-0's epilogue(0,0) pending.
                if (myhalf == 0) {
                    out[(size_t)batch * HID + wg * 16 + uu] = hvp;     // out row 0
                    ga = *(const f32x4*)(Gp + ((size_t)wg * MROWS + 32 + batch) * 64
                                         + uu * 4);                    // slice 1
                }
            }

            // ---- epilogue for half X (waves wv>>2 == X; wave-uniform) ----
            if (myhalf == X) {
                f32x4 gv = ga;                           // gates i,f,g,o of unit uu
                if (t > 0) {
#pragma unroll
                    for (int ks = 0; ks < 8; ++ks)
                        gv += *(const f32x4*)&SlT[ks][batch & 15][uu * 4];
                }
                float cn = sigf(gv[1]) * cs + sigf(gv[0]) * tanh_fast(gv[2]);
                cs = cn;
                float hv = sigf(gv[3]) * tanh_fast(cn);
                // publish h IMMEDIATELY (pairs = adjacent lanes via shfl_xor)
                u32 hw = (u32)f2bf(hv);
                u32 pw = (u32)__shfl_xor((int)hw, 1, 64);
                if ((lane & 1) == 0) {
                    store_u32_coh((u32*)(hb + (size_t)(t + 1) * (BATCH * HID)
                                            + (size_t)batch * HID + wg * 16 + uu),
                                  hw | (pw << 16));
                }
                hvp = hv;        // out-store + G prefetch deferred to next phase's hook
            }
        }
    }
    // tail: half-1's last pending out (row T-1). (half-0's was stored at hook(1,T-1).)
    if (myhalf == 1)
        out[((size_t)(T_STEPS - 1) * BATCH + batch) * HID + wg * 16 + uu] = hvp;
}

// ---------------- launch ----------------

extern "C" void kernel_launch(void* const* d_in, const int* in_sizes, int n_in,
                              void* d_out, int out_size, void* d_ws, size_t ws_size,
                              hipStream_t stream) {
    const float* x  = (const float*)d_in[0];   // T*B*D
    const float* Wx = (const float*)d_in[1];   // D x 4H
    const float* Wh = (const float*)d_in[2];   // H x 4H
    const float* b  = (const float*)d_in[3];   // 4H
    float* out = (float*)d_out;

    // workspace layout (bytes)
    char* ws = (char*)d_ws;
    const size_t OFF_XBF  = 0;                       // 8 MB  (4096x1024 bf16)
    const size_t OFF_WXT  = 8ull  << 20;             // 8 MB  (4096x1024 bf16)
    const size_t OFF_WHT  = 16ull << 20;             // 8 MB  (4096x1024 bf16)
    const size_t OFF_G    = 24ull << 20;             // 64 MB (64x4096x64 fp32 gate-minor)
    const size_t OFF_HB   = 88ull << 20;             // 129 * 64 KB = 8.0625 MB
    const size_t NEEDED   = OFF_HB + (size_t)(T_STEPS + 1) * BATCH * HID * 2;
    if (ws_size < NEEDED) return;  // loud failure (output stays poisoned)

    unsigned short* xbf = (unsigned short*)(ws + OFF_XBF);
    unsigned short* WxT = (unsigned short*)(ws + OFF_WXT);
    unsigned short* WhT = (unsigned short*)(ws + OFF_WHT);
    float*          Gp  = (float*)(ws + OFF_G);
    unsigned short* hb  = (unsigned short*)(ws + OFF_HB);

    // prep
    cast_f32_bf16<<<(MROWS * DIM / 4 + 255) / 256, 256, 0, stream>>>(x, xbf, MROWS * DIM);
    const int HBW = (T_STEPS + 1) * BATCH * HID / 2;    // u32 words in hb
    fill_sentinel<<<(HBW / 4 + 255) / 256, 256, 0, stream>>>((u32*)hb, HBW);
    dim3 tb(32, 8);
    transpose_cast<<<dim3(NGATE / 32, DIM / 32), tb, 0, stream>>>(Wx, WxT, DIM, NGATE);
    transpose_cast<<<dim3(NGATE / 32, HID / 32), tb, 0, stream>>>(Wh, WhT, HID, NGATE);

    // phase 1: all-timestep input GEMM (gate-minor permuted output)
    gemm_xw<<<dim3(NGATE / 128, MROWS / 128), 256, 0, stream>>>(xbf, WxT, b, Gp);

    // phase 2: persistent recurrence (batch-split two-phase pipeline)
    lstm_rec<<<NWGR, 512, 0, stream>>>(WhT, Gp, hb, out);
}

// Round 7
// 606.520 us; speedup vs baseline: 1.0399x; 1.0399x over previous
//
#include <hip/hip_runtime.h>
#include <hip/hip_bf16.h>
#include <stdint.h>

// Problem: T=128, B=32, D=1024, H=1024 LSTM unroll, fp32 in/out.
#define T_STEPS 128
#define BATCH   32
#define DIM     1024
#define HID     1024
#define NGATE   4096            // 4*H
#define MROWS   4096            // T*B
#define NWGR    64              // persistent recurrence workgroups (16 units each)

typedef unsigned int u32;
typedef __attribute__((ext_vector_type(8)))  __bf16 bf16x8;
typedef __attribute__((ext_vector_type(4)))  float  f32x4;
typedef __attribute__((ext_vector_type(4)))  u32    u32x4;

__device__ __forceinline__ unsigned short f2bf(float f) {
    u32 x = __float_as_uint(f);
    return (unsigned short)((x + 0x7fffu + ((x >> 16) & 1u)) >> 16);  // RNE
}
__device__ __forceinline__ float sigf(float x) {
    return 1.0f / (1.0f + __expf(-x));
}
__device__ __forceinline__ float tanh_fast(float x) {
    float ax = fabsf(x);
    float e  = __expf(-2.0f * ax);           // in (0,1], no overflow
    float t  = (1.0f - e) / (1.0f + e);
    return copysignf(t, x);
}
__device__ __forceinline__ u32 umax2(u32 a, u32 b) { return a > b ? a : b; }

// DEVICE-scope (agent) store: sc1 only. Bypasses L1 + per-XCD L2, served by
// the memory-side Infinity Cache. hb is ONLY touched through sc1 ops during
// lstm_rec -> no line of it ever lives in any L2 -> no fences needed.
__device__ __forceinline__ void store_u32_coh(u32* p, u32 v) {
    asm volatile("global_store_dword %0, %1, off sc1" :: "v"(p), "v"(v) : "memory");
}

// ---------------- prep kernels ----------------

__global__ void cast_f32_bf16(const float* __restrict__ in,
                              unsigned short* __restrict__ out, int n) {
    int idx = (blockIdx.x * blockDim.x + threadIdx.x) * 4;
    if (idx + 3 < n) {
        float4 v = *(const float4*)(in + idx);
        ushort4 o;
        o.x = f2bf(v.x); o.y = f2bf(v.y); o.z = f2bf(v.z); o.w = f2bf(v.w);
        *(ushort4*)(out + idx) = o;
    }
}

// sentinel fill: 0xFFFFFFFF = packed (NaN|NaN) bf16 pair; h is always finite
// and in (-1,1), so a real packed h can never equal the sentinel.
__global__ void fill_sentinel(u32* __restrict__ p, int n) {
    int i = (blockIdx.x * blockDim.x + threadIdx.x) * 4;
    if (i + 3 < n) {
        u32x4 v = {0xFFFFFFFFu, 0xFFFFFFFFu, 0xFFFFFFFFu, 0xFFFFFFFFu};
        *(u32x4*)(p + i) = v;
    }
}

// in: R x C fp32 (row-major) -> out: C x R bf16 (row-major transpose)
__global__ void transpose_cast(const float* __restrict__ in,
                               unsigned short* __restrict__ out, int R, int C) {
    __shared__ float tile[32][33];
    int c0 = blockIdx.x * 32, r0 = blockIdx.y * 32;
    int tx = threadIdx.x, ty = threadIdx.y;     // 32 x 8
#pragma unroll
    for (int i = 0; i < 4; ++i)
        tile[ty + i * 8][tx] = in[(size_t)(r0 + ty + i * 8) * C + c0 + tx];
    __syncthreads();
#pragma unroll
    for (int i = 0; i < 4; ++i)
        out[(size_t)(c0 + ty + i * 8) * R + r0 + tx] = f2bf(tile[tx][ty + i * 8]);
}

// ---------------- phase 1: Gp = perm(x @ Wx + b)  (bf16 MFMA, fp32 out) ----------------
// A: MROWS x DIM bf16 (x), BT: NGATE x DIM bf16 (WxT).
// Output in GATE-MINOR panels for the 64-WG recurrence:
//   orig col co = g*1024 + hu  ->  panel wg = hu>>4 (16 units), local unit u = hu&15,
//   panel col cp = u*4 + g  (so 4 gates of a unit are CONTIGUOUS -> f32x4 epilogue)
//   Gp[((size_t)wg*MROWS + row)*64 + cp]
__global__ __launch_bounds__(256) void gemm_xw(
    const unsigned short* __restrict__ A,
    const unsigned short* __restrict__ BT,
    const float* __restrict__ bias,
    float* __restrict__ Gp) {
    __shared__ unsigned short As[128 * 32];
    __shared__ unsigned short Bs[128 * 32];
    int tid  = threadIdx.x;
    int wave = tid >> 6, lane = tid & 63;
    int q = lane >> 4, c = lane & 15;
    int wm = wave >> 1, wn = wave & 1;
    int tm = blockIdx.y * 128, tn = blockIdx.x * 128;

    f32x4 acc[4][4] = {};

    const int srow0 = tid >> 2;           // 0..63
    const int srow1 = 64 + (tid >> 2);    // 64..127
    const int scol  = (tid & 3) * 8;      // bf16 elems

    u32x4 ra0, ra1, rb0, rb1;
    ra0 = *(const u32x4*)(A  + (size_t)(tm + srow0) * DIM + scol);
    ra1 = *(const u32x4*)(A  + (size_t)(tm + srow1) * DIM + scol);
    rb0 = *(const u32x4*)(BT + (size_t)(tn + srow0) * DIM + scol);
    rb1 = *(const u32x4*)(BT + (size_t)(tn + srow1) * DIM + scol);

    for (int kk = 0; kk < 32; ++kk) {
        __syncthreads();
        *(u32x4*)(As + srow0 * 32 + scol) = ra0;
        *(u32x4*)(As + srow1 * 32 + scol) = ra1;
        *(u32x4*)(Bs + srow0 * 32 + scol) = rb0;
        *(u32x4*)(Bs + srow1 * 32 + scol) = rb1;
        __syncthreads();
        if (kk < 31) {
            int ko = (kk + 1) * 32 + scol;
            ra0 = *(const u32x4*)(A  + (size_t)(tm + srow0) * DIM + ko);
            ra1 = *(const u32x4*)(A  + (size_t)(tm + srow1) * DIM + ko);
            rb0 = *(const u32x4*)(BT + (size_t)(tn + srow0) * DIM + ko);
            rb1 = *(const u32x4*)(BT + (size_t)(tn + srow1) * DIM + ko);
        }
        bf16x8 af[4], bfv[4];
#pragma unroll
        for (int i = 0; i < 4; ++i) {
            af[i]  = *(const bf16x8*)(As + (wm * 64 + i * 16 + c) * 32 + q * 8);
            bfv[i] = *(const bf16x8*)(Bs + (wn * 64 + i * 16 + c) * 32 + q * 8);
        }
#pragma unroll
        for (int i = 0; i < 4; ++i)
#pragma unroll
            for (int j = 0; j < 4; ++j)
                acc[i][j] = __builtin_amdgcn_mfma_f32_16x16x32_bf16(
                    af[i], bfv[j], acc[i][j], 0, 0, 0);
    }
    // epilogue: C/D layout col = lane&15, row = quad*4 + reg; gate-minor store
#pragma unroll
    for (int j = 0; j < 4; ++j) {
        int co = tn + wn * 64 + j * 16 + c;
        float bj = bias[co];
        int g = co >> 10, hu = co & 1023;
        int wgr = hu >> 4, u = hu & 15;
        int cp = u * 4 + g;
#pragma unroll
        for (int i = 0; i < 4; ++i) {
            int row0 = tm + wm * 64 + i * 16 + q * 4;
#pragma unroll
            for (int r = 0; r < 4; ++r)
                Gp[((size_t)wgr * MROWS + row0 + r) * 64 + cp] = acc[i][j][r] + bj;
        }
    }
}

// ---------------- phase 2: persistent recurrence, pipelined batch-split ----------------
// 64 WGs x 512 threads (8 waves). WG wg owns 16 hidden units (64 gate-minor cols).
// Two phases per step (half X = batches X*16..X*16+16) -- independent sub-LSTMs.
//
// R7 fixes R6's two flaws:
//  1. 16x16x32 MFMA (gemm_xw's verified fragment layout): 16 MFMAs/phase
//     -> 2 phases = exactly R3's FLOPs (R6 wasted 2x on discarded rows).
//  2. ISSUE-EARLY / WAIT-LATE poll: each wave issues its 4 h-loads for the
//     NEXT phase right after MFMA+dump, holds them in flight across
//     barB + epilogue + next phase entry (~1200cy). Next phase does only
//     vmcnt(0) + sentinel check (sched_barrier(0) after the wait -- rule #18).
//     The IC round-trip that R6 paid serially per phase is now overlapped;
//     the residual drain is our own h-store ack (= protocol pacing).
// R4-hazard audit: ga consumed (step 3) BEFORE the h-issue point; out-store
// issues at step 3 (1 phase of aging); so every conservative vmcnt(0) the
// compiler emits lands where all in-flight ops are >=1 phase old.
// Wave wv = K-eighth (128 k). Per phase: wave stages its 4KB slab (rows
// wv*2..wv*2+1 local), barA, 4 ds_reads + 16 MFMAs (4 indep acc chains),
// dump SlT[8][16][64], issue next loads, barB, epilogue on tid<256.
// Hs halves overwrite each phase (safe: barB(p) fences all MFMA reads before
// any stage(p+1) write). Sentinel protocol unchanged (correctness-safe:
// stale data can only cause retries, never wrong values).
__global__ __launch_bounds__(512, 1) void lstm_rec(
    const unsigned short* __restrict__ WhT,   // NGATE x DIM bf16
    const float* __restrict__ Gp,             // gate-minor panels, 64 x 4096 x 64 fp32
    unsigned short* hb,                       // (T+1) x BATCH x HID bf16 (slot 0 unused)
    float* __restrict__ out) {                // T x BATCH x HID fp32
    __shared__ unsigned short Hs[16][1024];   // 32 KB, row = local batch, XOR-swizzled
    __shared__ float SlT[8][16][64];          // 32 KB, [ks][local b][panel col]
    const int wg = blockIdx.x, tid = threadIdx.x;
    const int wv = tid >> 6, lane = tid & 63;
    const int l15 = lane & 15, g4 = lane >> 4;

    // ---- B-fragments (Wh) into registers, once: br[ct*4 + kc] ----
    // 16x16x32 B-layout (gemm_xw convention): col = lane&15, k = (lane>>4)*8 + j
    bf16x8 br[16];
#pragma unroll
    for (int ct = 0; ct < 4; ++ct) {
        const int cp = ct * 16 + l15, u = cp >> 2, g = cp & 3;
        const unsigned short* w = WhT + (size_t)(g * HID + wg * 16 + u) * DIM
                                + wv * 128 + g4 * 8;
#pragma unroll
        for (int kc = 0; kc < 4; ++kc)
            br[ct * 4 + kc] = *(const bf16x8*)(w + kc * 32);
    }

    // epilogue mapping (tid<256): thread = (local batch bl, unit uu)
    const int bl = (tid >> 4) & 15, uu = tid & 15;
    float cs0 = 0.f, cs1 = 0.f;               // cell state per half (static names)
    float hvp = 0.f;                          // pending out value (stored next phase)
    f32x4 ga0 = {}, ga1 = {};
    if (tid < 256) {
        ga0 = *(const f32x4*)(Gp + ((size_t)wg * MROWS + 0 * 32 + 0  + bl) * 64 + uu * 4);
        ga1 = *(const f32x4*)(Gp + ((size_t)wg * MROWS + 0 * 32 + 16 + bl) * 64 + uu * 4);
    }

    char* hs_base = (char*)&Hs[0][0];
    const char* hbB = (const char*)hb;
    const int rxor = l15 << 4;                // read-side swizzle constant
    u32x4 h0 = {}, h1 = {}, h2 = {}, h3 = {}; // early-issued h loads (in flight)

    for (int t = 0; t < T_STEPS; ++t) {
#pragma unroll
        for (int X = 0; X < 2; ++X) {
            f32x4 acc0 = {}, acc1 = {}, acc2 = {}, acc3 = {};
            if (t > 0) {
                // ---- complete the early-issued loads; sentinel check ----
                asm volatile("s_waitcnt vmcnt(0)" ::: "memory");
                __builtin_amdgcn_sched_barrier(0);
                u32 m = umax2(umax2(umax2(umax2(h0[0], h0[1]), umax2(h0[2], h0[3])),
                                    umax2(umax2(h1[0], h1[1]), umax2(h1[2], h1[3]))),
                              umax2(umax2(umax2(h2[0], h2[1]), umax2(h2[2], h2[3])),
                                    umax2(umax2(h3[0], h3[1]), umax2(h3[2], h3[3]))));
                while (__any((int)(m == 0xFFFFFFFFu))) {
                    const char* pc = hbB + ((size_t)t << 16) + (X << 15)
                                   + (wv << 12) + (size_t)lane * 16;
                    asm volatile(
                        "global_load_dwordx4 %0, %4, off sc1\n\t"
                        "global_load_dwordx4 %1, %4, off offset:1024 sc1\n\t"
                        "global_load_dwordx4 %2, %4, off offset:2048 sc1\n\t"
                        "global_load_dwordx4 %3, %4, off offset:3072 sc1\n\t"
                        "s_waitcnt vmcnt(0)"
                        : "=&v"(h0), "=&v"(h1), "=&v"(h2), "=&v"(h3)
                        : "v"(pc) : "memory");
                    m = umax2(umax2(umax2(umax2(h0[0], h0[1]), umax2(h0[2], h0[3])),
                                    umax2(umax2(h1[0], h1[1]), umax2(h1[2], h1[3]))),
                              umax2(umax2(umax2(h2[0], h2[1]), umax2(h2[2], h2[3])),
                                    umax2(umax2(h3[0], h3[1]), umax2(h3[2], h3[3]))));
                }
                // ---- stage 4KB slab: local rows wv*2, wv*2+1 (swizzled) ----
                {
                    int r0 = wv << 1, r1 = r0 + 1;
                    int cb0 = lane * 16, cb1 = 1024 + lane * 16;
                    *(u32x4*)(hs_base + (r0 << 11) + (cb0 ^ (r0 << 4))) = h0;
                    *(u32x4*)(hs_base + (r0 << 11) + (cb1 ^ (r0 << 4))) = h1;
                    *(u32x4*)(hs_base + (r1 << 11) + (cb0 ^ (r1 << 4))) = h2;
                    *(u32x4*)(hs_base + (r1 << 11) + (cb1 ^ (r1 << 4))) = h3;
                }
                asm volatile("s_waitcnt lgkmcnt(0)" ::: "memory");
                __builtin_amdgcn_s_barrier();            // barrier A: Hs half ready
            }

            // ---- step 3a (vmem, waves 0-3): consume ga FIRST, then issue ----
            f32x4 gvb = {};
            if (tid < 256) {
                gvb = X ? ga1 : ga0;          // conservative vmem wait lands HERE (all old)
                if (t > 0 || X > 0) {         // pending out from previous phase
                    const int tp = X ? t : t - 1;
                    out[((size_t)tp * BATCH + (1 - X) * 16 + bl) * HID + wg * 16 + uu] = hvp;
                }
                if (t + 1 < T_STEPS) {        // next G slice, same half (2-phase aging)
                    f32x4 gn = *(const f32x4*)(Gp + ((size_t)wg * MROWS
                              + (size_t)(t + 1) * 32 + X * 16 + bl) * 64 + uu * 4);
                    if (X) ga1 = gn; else ga0 = gn;
                }
            }

            if (t > 0) {
                // ---- 4 ds_read_b128 + 16 MFMAs (4 independent acc chains) ----
                const char* hrow = hs_base + (l15 << 11);
#pragma unroll
                for (int kc = 0; kc < 4; ++kc) {
                    int cb = ((wv << 8) + (kc << 6) + (g4 << 4)) ^ rxor;
                    bf16x8 a = *(const bf16x8*)(hrow + cb);
                    acc0 = __builtin_amdgcn_mfma_f32_16x16x32_bf16(a, br[kc],      acc0, 0, 0, 0);
                    acc1 = __builtin_amdgcn_mfma_f32_16x16x32_bf16(a, br[4 + kc],  acc1, 0, 0, 0);
                    acc2 = __builtin_amdgcn_mfma_f32_16x16x32_bf16(a, br[8 + kc],  acc2, 0, 0, 0);
                    acc3 = __builtin_amdgcn_mfma_f32_16x16x32_bf16(a, br[12 + kc], acc3, 0, 0, 0);
                }
                // ---- dump: C layout col = lane&15, row = (lane>>4)*4 + r ----
#pragma unroll
                for (int r = 0; r < 4; ++r) {
                    const int b = g4 * 4 + r;
                    SlT[wv][b][l15]      = acc0[r];
                    SlT[wv][b][16 + l15] = acc1[r];
                    SlT[wv][b][32 + l15] = acc2[r];
                    SlT[wv][b][48 + l15] = acc3[r];
                }
            }

            // ---- issue h-loads for the NEXT phase (in flight across epilogue) ----
            {
                const int tn = X ? (t + 1) : t;          // next phase = (1-X, tn)
                if (tn >= 1 && tn < T_STEPS) {
                    const char* pn = hbB + ((size_t)tn << 16) + ((1 - X) << 15)
                                   + (wv << 12) + (size_t)lane * 16;
                    asm volatile(
                        "global_load_dwordx4 %0, %4, off sc1\n\t"
                        "global_load_dwordx4 %1, %4, off offset:1024 sc1\n\t"
                        "global_load_dwordx4 %2, %4, off offset:2048 sc1\n\t"
                        "global_load_dwordx4 %3, %4, off offset:3072 sc1"
                        : "=&v"(h0), "=&v"(h1), "=&v"(h2), "=&v"(h3)
                        : "v"(pn) : "memory");
                }
            }

            if (t > 0) {
                asm volatile("s_waitcnt lgkmcnt(0)" ::: "memory");
                __builtin_amdgcn_s_barrier();            // barrier B: SlT ready
            }

            // ---- epilogue (tid<256): one output (X*16+bl, uu) per thread ----
            if (tid < 256) {
                f32x4 gv = gvb;
                if (t > 0) {
#pragma unroll
                    for (int ks = 0; ks < 8; ++ks)
                        gv += *(const f32x4*)&SlT[ks][bl][uu * 4];
                }
                float cs = X ? cs1 : cs0;
                float cn = sigf(gv[1]) * cs + sigf(gv[0]) * tanh_fast(gv[2]);
                if (X) cs1 = cn; else cs0 = cn;
                float hv = sigf(gv[3]) * tanh_fast(cn);
                // publish h immediately (pairs = adjacent lanes)
                u32 hw = (u32)f2bf(hv);
                u32 pw = (u32)__shfl_xor((int)hw, 1, 64);
                if ((lane & 1) == 0) {
                    store_u32_coh((u32*)(hb + (size_t)(t + 1) * (BATCH * HID)
                                            + (size_t)(X * 16 + bl) * HID + wg * 16 + uu),
                                  hw | (pw << 16));
                }
                hvp = hv;            // out-store happens at the next phase's step 3
            }
        }
    }
    // tail: last pending out (phase (1, T-1): row T-1, batches 16..31)
    if (tid < 256)
        out[((size_t)(T_STEPS - 1) * BATCH + 16 + bl) * HID + wg * 16 + uu] = hvp;
}

// ---------------- launch ----------------

extern "C" void kernel_launch(void* const* d_in, const int* in_sizes, int n_in,
                              void* d_out, int out_size, void* d_ws, size_t ws_size,
                              hipStream_t stream) {
    const float* x  = (const float*)d_in[0];   // T*B*D
    const float* Wx = (const float*)d_in[1];   // D x 4H
    const float* Wh = (const float*)d_in[2];   // H x 4H
    const float* b  = (const float*)d_in[3];   // 4H
    float* out = (float*)d_out;

    // workspace layout (bytes)
    char* ws = (char*)d_ws;
    const size_t OFF_XBF  = 0;                       // 8 MB  (4096x1024 bf16)
    const size_t OFF_WXT  = 8ull  << 20;             // 8 MB  (4096x1024 bf16)
    const size_t OFF_WHT  = 16ull << 20;             // 8 MB  (4096x1024 bf16)
    const size_t OFF_G    = 24ull << 20;             // 64 MB (64x4096x64 fp32 gate-minor)
    const size_t OFF_HB   = 88ull << 20;             // 129 * 64 KB = 8.0625 MB
    const size_t NEEDED   = OFF_HB + (size_t)(T_STEPS + 1) * BATCH * HID * 2;
    if (ws_size < NEEDED) return;  // loud failure (output stays poisoned)

    unsigned short* xbf = (unsigned short*)(ws + OFF_XBF);
    unsigned short* WxT = (unsigned short*)(ws + OFF_WXT);
    unsigned short* WhT = (unsigned short*)(ws + OFF_WHT);
    float*          Gp  = (float*)(ws + OFF_G);
    unsigned short* hb  = (unsigned short*)(ws + OFF_HB);

    // prep
    cast_f32_bf16<<<(MROWS * DIM / 4 + 255) / 256, 256, 0, stream>>>(x, xbf, MROWS * DIM);
    const int HBW = (T_STEPS + 1) * BATCH * HID / 2;    // u32 words in hb
    fill_sentinel<<<(HBW / 4 + 255) / 256, 256, 0, stream>>>((u32*)hb, HBW);
    dim3 tb(32, 8);
    transpose_cast<<<dim3(NGATE / 32, DIM / 32), tb, 0, stream>>>(Wx, WxT, DIM, NGATE);
    transpose_cast<<<dim3(NGATE / 32, HID / 32), tb, 0, stream>>>(Wh, WhT, HID, NGATE);

    // phase 1: all-timestep input GEMM (gate-minor permuted output)
    gemm_xw<<<dim3(NGATE / 128, MROWS / 128), 256, 0, stream>>>(xbf, WxT, b, Gp);

    // phase 2: persistent recurrence (pipelined batch-split)
    lstm_rec<<<NWGR, 512, 0, stream>>>(WhT, Gp, hb, out);
}

// Round 8
// 480.063 us; speedup vs baseline: 1.3139x; 1.2634x over previous
//
#include <hip/hip_runtime.h>
#include <hip/hip_bf16.h>
#include <stdint.h>

// Problem: T=128, B=32, D=1024, H=1024 LSTM unroll, fp32 in/out.
#define T_STEPS 128
#define BATCH   32
#define DIM     1024
#define HID     1024
#define NGATE   4096            // 4*H
#define MROWS   4096            // T*B
#define NWGR    64              // persistent recurrence workgroups (16 units each)

typedef unsigned int u32;
typedef __attribute__((ext_vector_type(8)))  __bf16 bf16x8;
typedef __attribute__((ext_vector_type(4)))  float  f32x4;
typedef __attribute__((ext_vector_type(16))) float  f32x16;
typedef __attribute__((ext_vector_type(4)))  u32    u32x4;

__device__ __forceinline__ unsigned short f2bf(float f) {
    u32 x = __float_as_uint(f);
    return (unsigned short)((x + 0x7fffu + ((x >> 16) & 1u)) >> 16);  // RNE
}
__device__ __forceinline__ float sigf(float x) {
    return 1.0f / (1.0f + __expf(-x));
}
__device__ __forceinline__ float tanh_fast(float x) {
    float ax = fabsf(x);
    float e  = __expf(-2.0f * ax);           // in (0,1], no overflow
    float t  = (1.0f - e) / (1.0f + e);
    return copysignf(t, x);
}
__device__ __forceinline__ u32 umax2(u32 a, u32 b) { return a > b ? a : b; }

// DEVICE-scope (agent) store: sc1 only. Bypasses L1 + per-XCD L2, served by
// the memory-side Infinity Cache. hb is ONLY touched through sc1 ops during
// lstm_rec -> no line of it ever lives in any L2 -> no fences needed.
__device__ __forceinline__ void store_u32_coh(u32* p, u32 v) {
    asm volatile("global_store_dword %0, %1, off sc1" :: "v"(p), "v"(v) : "memory");
}

// ---------------- prep kernels ----------------

// sentinel fill: 0xFFFFFFFF = packed (NaN|NaN) bf16 pair; h is always finite
// and in (-1,1), so a real packed h can never equal the sentinel.
__global__ void fill_sentinel(u32* __restrict__ p, int n) {
    int i = (blockIdx.x * blockDim.x + threadIdx.x) * 4;
    if (i + 3 < n) {
        u32x4 v = {0xFFFFFFFFu, 0xFFFFFFFFu, 0xFFFFFFFFu, 0xFFFFFFFFu};
        *(u32x4*)(p + i) = v;
    }
}

// in: R x C fp32 (row-major) -> out: C x R bf16 with rows in GATE-MINOR
// permuted order: original col cc = g*1024 + hu  ->  out row rp = hu*4 + g.
// (C = NGATE always here; R = 1024.) Makes the GEMM's N dimension gate-minor,
// so gemm_xw's epilogue writes Gp fully coalesced (R8 fix: the old layout
// wrote single floats at 16B stride -> 25%-efficient HBM writes of 64MB).
__global__ void transpose_cast(const float* __restrict__ in,
                               unsigned short* __restrict__ out, int R, int C) {
    __shared__ float tile[32][33];
    int c0 = blockIdx.x * 32, r0 = blockIdx.y * 32;
    int tx = threadIdx.x, ty = threadIdx.y;     // 32 x 8
#pragma unroll
    for (int i = 0; i < 4; ++i)
        tile[ty + i * 8][tx] = in[(size_t)(r0 + ty + i * 8) * C + c0 + tx];
    __syncthreads();
#pragma unroll
    for (int i = 0; i < 4; ++i) {
        int cc = c0 + ty + i * 8;                       // original col (0..NGATE)
        int rp = ((cc & 1023) << 2) | (cc >> 10);       // gate-minor row
        out[(size_t)rp * R + r0 + tx] = f2bf(tile[tx][ty + i * 8]);
    }
}

// ---------------- phase 1: Gp = perm(x @ Wx + b)  (bf16 MFMA, fp32 out) ----------------
// A: MROWS x DIM fp32 (x; cast to bf16 in-register during staging -- the old
// separate cast kernel is gone). BT: NGATE x DIM bf16, rows ALREADY gate-minor
// (transpose_cast perm), so output col co is the gate-minor index hu*4+g.
// Epilogue: wgr = co>>6 (panel), cp = co&63 -> identical Gp layout to before,
// but lanes c=0..15 now write 16 CONSECUTIVE floats (64B chunks, coalesced).
__global__ __launch_bounds__(256) void gemm_xw(
    const float* __restrict__ A,
    const unsigned short* __restrict__ BT,
    const float* __restrict__ bias,
    float* __restrict__ Gp) {
    __shared__ unsigned short As[128 * 32];
    __shared__ unsigned short Bs[128 * 32];
    int tid  = threadIdx.x;
    int wave = tid >> 6, lane = tid & 63;
    int q = lane >> 4, c = lane & 15;
    int wm = wave >> 1, wn = wave & 1;
    int tm = blockIdx.y * 128, tn = blockIdx.x * 128;

    f32x4 acc[4][4] = {};

    const int srow0 = tid >> 2;           // 0..63
    const int srow1 = 64 + (tid >> 2);    // 64..127
    const int scol  = (tid & 3) * 8;      // element index (8 per thread)

    float4 a0l, a0h, a1l, a1h;
    u32x4 rb0, rb1;
    a0l = *(const float4*)(A + (size_t)(tm + srow0) * DIM + scol);
    a0h = *(const float4*)(A + (size_t)(tm + srow0) * DIM + scol + 4);
    a1l = *(const float4*)(A + (size_t)(tm + srow1) * DIM + scol);
    a1h = *(const float4*)(A + (size_t)(tm + srow1) * DIM + scol + 4);
    rb0 = *(const u32x4*)(BT + (size_t)(tn + srow0) * DIM + scol);
    rb1 = *(const u32x4*)(BT + (size_t)(tn + srow1) * DIM + scol);

    for (int kk = 0; kk < 32; ++kk) {
        __syncthreads();
        {
            u32x4 pa0 = { (u32)f2bf(a0l.x) | ((u32)f2bf(a0l.y) << 16),
                          (u32)f2bf(a0l.z) | ((u32)f2bf(a0l.w) << 16),
                          (u32)f2bf(a0h.x) | ((u32)f2bf(a0h.y) << 16),
                          (u32)f2bf(a0h.z) | ((u32)f2bf(a0h.w) << 16) };
            u32x4 pa1 = { (u32)f2bf(a1l.x) | ((u32)f2bf(a1l.y) << 16),
                          (u32)f2bf(a1l.z) | ((u32)f2bf(a1l.w) << 16),
                          (u32)f2bf(a1h.x) | ((u32)f2bf(a1h.y) << 16),
                          (u32)f2bf(a1h.z) | ((u32)f2bf(a1h.w) << 16) };
            *(u32x4*)(As + srow0 * 32 + scol) = pa0;
            *(u32x4*)(As + srow1 * 32 + scol) = pa1;
            *(u32x4*)(Bs + srow0 * 32 + scol) = rb0;
            *(u32x4*)(Bs + srow1 * 32 + scol) = rb1;
        }
        __syncthreads();
        if (kk < 31) {
            int ko = (kk + 1) * 32 + scol;
            a0l = *(const float4*)(A + (size_t)(tm + srow0) * DIM + ko);
            a0h = *(const float4*)(A + (size_t)(tm + srow0) * DIM + ko + 4);
            a1l = *(const float4*)(A + (size_t)(tm + srow1) * DIM + ko);
            a1h = *(const float4*)(A + (size_t)(tm + srow1) * DIM + ko + 4);
            rb0 = *(const u32x4*)(BT + (size_t)(tn + srow0) * DIM + ko);
            rb1 = *(const u32x4*)(BT + (size_t)(tn + srow1) * DIM + ko);
        }
        bf16x8 af[4], bfv[4];
#pragma unroll
        for (int i = 0; i < 4; ++i) {
            af[i]  = *(const bf16x8*)(As + (wm * 64 + i * 16 + c) * 32 + q * 8);
            bfv[i] = *(const bf16x8*)(Bs + (wn * 64 + i * 16 + c) * 32 + q * 8);
        }
#pragma unroll
        for (int i = 0; i < 4; ++i)
#pragma unroll
            for (int j = 0; j < 4; ++j)
                acc[i][j] = __builtin_amdgcn_mfma_f32_16x16x32_bf16(
                    af[i], bfv[j], acc[i][j], 0, 0, 0);
    }
    // epilogue: C/D layout col = lane&15, row = quad*4 + reg.
    // co is ALREADY gate-minor; bias needs the inverse perm.
#pragma unroll
    for (int j = 0; j < 4; ++j) {
        int co = tn + wn * 64 + j * 16 + c;             // gate-minor col hu*4+g
        float bj = bias[(co & 3) * 1024 + (co >> 2)];
        int wgr = co >> 6, cp = co & 63;
#pragma unroll
        for (int i = 0; i < 4; ++i) {
            int row0 = tm + wm * 64 + i * 16 + q * 4;
#pragma unroll
            for (int r = 0; r < 4; ++r)
                Gp[((size_t)wgr * MROWS + row0 + r) * 64 + cp] = acc[i][j][r] + bj;
        }
    }
}

// ---------------- phase 2: persistent recurrence (EXACT R3 structure, 330us) ----------------
// 64 WGs x 512 threads (8 waves). WG wg owns 16 hidden units -> 64 gate-minor
// panel cols (2 MFMA col-tiles of 32). Wave wv = K-EIGHTH (128 k); each
// A-fragment read feeds BOTH col-tiles (zero A-read redundancy).
// Sentinel protocol, slab staging, Hs XOR-swizzle unchanged.
// Only change vs R3: WhT rows are gate-minor now -> B-frag row = wg*64 (+32) + ln.
__global__ __launch_bounds__(512, 1) void lstm_rec(
    const unsigned short* __restrict__ WhT,   // NGATE x DIM bf16, gate-minor rows
    const float* __restrict__ Gp,             // gate-minor panels, 64 x 4096 x 64 fp32
    unsigned short* hb,                       // (T+1) x BATCH x HID bf16 (slot 0 unused)
    float* __restrict__ out) {                // T x BATCH x HID fp32
    __shared__ unsigned short Hs[32][1024];   // h tile, XOR-swizzled rows (64 KB)
    __shared__ float SlT[8][32][64];          // K-eighth partials [ks][b][panel col] (64 KB)
    __shared__ unsigned short Ht[32][16];     // h bf16 pack tile (1 KB)
    const int wg = blockIdx.x, tid = threadIdx.x;
    const int wv = tid >> 6, lane = tid & 63;
    const int ln = lane & 31, lh = lane >> 5;

    // ---- stage B-fragments (Wh) into registers, once ----
    // B-frag (32x32x16): col = lane&31 = panel col (gate-minor), k = wv*128 + kk*16 + lh*8 + j
    bf16x8 br0[8], br1[8];
    {
        const unsigned short* w0 =
            WhT + (size_t)(wg * 64 + ln) * DIM + wv * 128 + lh * 8;
        const unsigned short* w1 =
            WhT + (size_t)(wg * 64 + 32 + ln) * DIM + wv * 128 + lh * 8;
#pragma unroll
        for (int kk = 0; kk < 8; ++kk) {
            br0[kk] = *(const bf16x8*)(w0 + kk * 16);
            br1[kk] = *(const bf16x8*)(w1 + kk * 16);
        }
    }

    // epilogue mapping: thread = (batch, u); ONE output per thread
    const int batch = tid >> 4, uu = tid & 15;
    float cs = 0.f;
    // G prefetch for t=0 (gate-minor: f32x4 = 4 gates of unit uu)
    f32x4 ga = *(const f32x4*)(Gp + ((size_t)wg * MROWS + batch) * 64 + uu * 4);

    char* hs_base = (char*)&Hs[0][0];
    const int rxor = (ln & 15) << 4;          // read-side swizzle constant

    for (int t = 0; t < T_STEPS; ++t) {
        if (t > 0) {
            // ---- coalesced, sentinel-validated h load (wave-local retry) ----
            // flat byte layout of slot t: batch*2048 + unit*2 (row-major).
            // wave wv owns bytes [wv*8K, wv*8K+8K): 8 instrs x 1KB contiguous.
            const char* p0 = (const char*)hb + ((size_t)t << 16)
                           + ((size_t)wv << 13) + (size_t)lane * 16;
            const char* p1 = p0 + 4096;
            u32x4 h[8];
            for (;;) {
                asm volatile(
                    "global_load_dwordx4 %0, %8, off sc1\n\t"
                    "global_load_dwordx4 %1, %8, off offset:1024 sc1\n\t"
                    "global_load_dwordx4 %2, %8, off offset:2048 sc1\n\t"
                    "global_load_dwordx4 %3, %8, off offset:3072 sc1\n\t"
                    "global_load_dwordx4 %4, %9, off sc1\n\t"
                    "global_load_dwordx4 %5, %9, off offset:1024 sc1\n\t"
                    "global_load_dwordx4 %6, %9, off offset:2048 sc1\n\t"
                    "global_load_dwordx4 %7, %9, off offset:3072 sc1\n\t"
                    "s_waitcnt vmcnt(0)"
                    : "=&v"(h[0]), "=&v"(h[1]), "=&v"(h[2]), "=&v"(h[3]),
                      "=&v"(h[4]), "=&v"(h[5]), "=&v"(h[6]), "=&v"(h[7])
                    : "v"(p0), "v"(p1)
                    : "memory");
                u32 m = 0;
#pragma unroll
                for (int i = 0; i < 8; ++i) {
                    u32 a = umax2(umax2(h[i][0], h[i][1]),
                                  umax2(h[i][2], h[i][3]));
                    m = umax2(m, a);
                }
                if (!__any((int)(m == 0xFFFFFFFFu))) break;
            }
            // ---- stage into swizzled LDS (R2 formula, unchanged) ----
#pragma unroll
            for (int j = 0; j < 8; ++j) {
                int row  = (wv << 2) + (j >> 1);
                int colb = ((j & 1) << 10) + lane * 16;
                int off  = (row << 11) + (colb ^ ((row & 15) << 4));
                *(u32x4*)(hs_base + off) = h[j];
            }
            asm volatile("s_waitcnt lgkmcnt(0)" ::: "memory");
            __builtin_amdgcn_s_barrier();            // barrier A: Hs ready

            // ---- K-eighth: 8 A-reads, 16 MFMAs (each read feeds BOTH tiles) ----
            // A-frag (32x32x16): row = lane&31 (batch), k = wv*128 + kk*16 + lh*8 + j
            f32x16 acc0 = {}, acc1 = {};
            const char* hrow = hs_base + (ln << 11);
#pragma unroll
            for (int kk = 0; kk < 8; ++kk) {
                int cb = ((wv << 8) + (kk << 5) + (lh << 4)) ^ rxor;
                bf16x8 a = *(const bf16x8*)(hrow + cb);
                acc0 = __builtin_amdgcn_mfma_f32_32x32x16_bf16(a, br0[kk], acc0, 0, 0, 0);
                acc1 = __builtin_amdgcn_mfma_f32_32x32x16_bf16(a, br1[kk], acc1, 0, 0, 0);
            }

            // ---- dump partials: SlT[ks][b][col], banks = ln -> conflict-free ----
            // C layout 32x32: col = lane&31, b = (reg&3) + 8*(reg>>2) + 4*(lane>>5)
#pragma unroll
            for (int rg = 0; rg < 4; ++rg)
#pragma unroll
                for (int rr = 0; rr < 4; ++rr) {
                    const int bb = rg * 8 + lh * 4 + rr;
                    SlT[wv][bb][ln]      = acc0[rg * 4 + rr];
                    SlT[wv][bb][32 + ln] = acc1[rg * 4 + rr];
                }
            asm volatile("s_waitcnt lgkmcnt(0)" ::: "memory");
            __builtin_amdgcn_s_barrier();            // barrier B: SlT ready
        }

        // ---- epilogue: ONE output (batch, unit uu) per thread ----
        f32x4 gv = ga;                               // gates i,f,g,o of unit uu
        if (t > 0) {
#pragma unroll
            for (int ks = 0; ks < 8; ++ks)
                gv += *(const f32x4*)&SlT[ks][batch][uu * 4];
        }
        float cn = sigf(gv[1]) * cs + sigf(gv[0]) * tanh_fast(gv[2]);
        cs = cn;
        float hv = sigf(gv[3]) * tanh_fast(cn);

        // pack h pairs via in-wave LDS bounce (Ht rows 4b per wave: in-wave only)
        Ht[batch][uu] = f2bf(hv);
        asm volatile("s_waitcnt lgkmcnt(0)" ::: "memory");
        if ((uu & 1) == 0) {
            u32 packed = *(const u32*)&Ht[batch][uu];
            store_u32_coh((u32*)(hb + (size_t)(t + 1) * (BATCH * HID)
                                    + (size_t)batch * HID + wg * 16 + uu), packed);
        }

        // off the critical path: G prefetch for step t+1 + out-store
        if (t + 1 < T_STEPS)
            ga = *(const f32x4*)(Gp + ((size_t)wg * MROWS + (size_t)(t + 1) * 32 + batch) * 64
                                 + uu * 4);
        out[((size_t)t * BATCH + batch) * HID + wg * 16 + uu] = hv;
        // no end-of-loop barrier: stage(t+1) Hs writes are sentinel-gated behind
        // every wave's h-store(t+1), which follows its SlT/Hs reads of step t.
    }
}

// ---------------- launch ----------------

extern "C" void kernel_launch(void* const* d_in, const int* in_sizes, int n_in,
                              void* d_out, int out_size, void* d_ws, size_t ws_size,
                              hipStream_t stream) {
    const float* x  = (const float*)d_in[0];   // T*B*D
    const float* Wx = (const float*)d_in[1];   // D x 4H
    const float* Wh = (const float*)d_in[2];   // H x 4H
    const float* b  = (const float*)d_in[3];   // 4H
    float* out = (float*)d_out;

    // workspace layout (bytes)
    char* ws = (char*)d_ws;
    const size_t OFF_WXT  = 8ull  << 20;             // 8 MB  (4096x1024 bf16, gate-minor rows)
    const size_t OFF_WHT  = 16ull << 20;             // 8 MB  (4096x1024 bf16, gate-minor rows)
    const size_t OFF_G    = 24ull << 20;             // 64 MB (64x4096x64 fp32 gate-minor)
    const size_t OFF_HB   = 88ull << 20;             // 129 * 64 KB = 8.0625 MB
    const size_t NEEDED   = OFF_HB + (size_t)(T_STEPS + 1) * BATCH * HID * 2;
    if (ws_size < NEEDED) return;  // loud failure (output stays poisoned)

    unsigned short* WxT = (unsigned short*)(ws + OFF_WXT);
    unsigned short* WhT = (unsigned short*)(ws + OFF_WHT);
    float*          Gp  = (float*)(ws + OFF_G);
    unsigned short* hb  = (unsigned short*)(ws + OFF_HB);

    // prep (the fp32->bf16 cast of x is fused into gemm_xw's A-staging now)
    const int HBW = (T_STEPS + 1) * BATCH * HID / 2;    // u32 words in hb
    fill_sentinel<<<(HBW / 4 + 255) / 256, 256, 0, stream>>>((u32*)hb, HBW);
    dim3 tb(32, 8);
    transpose_cast<<<dim3(NGATE / 32, DIM / 32), tb, 0, stream>>>(Wx, WxT, DIM, NGATE);
    transpose_cast<<<dim3(NGATE / 32, HID / 32), tb, 0, stream>>>(Wh, WhT, HID, NGATE);

    // phase 1: all-timestep input GEMM (gate-minor output, coalesced writes)
    gemm_xw<<<dim3(NGATE / 128, MROWS / 128), 256, 0, stream>>>(x, WxT, b, Gp);

    // phase 2: persistent recurrence (exact R3 structure)
    lstm_rec<<<NWGR, 512, 0, stream>>>(WhT, Gp, hb, out);
}